// Round 1
// baseline (113.007 us; speedup 1.0000x reference)
//
#include <hip/hip_runtime.h>

#define BS 16
#define CH 256
#define TT 2048

// ---------------------------------------------------------------------------
// Transpose input (BS, CH, TT) -> (BS, TT, CH) so per-tap reads across
// channels are coalesced (lane = channel, t is wave-uniform).
// ---------------------------------------------------------------------------
__global__ __launch_bounds__(256) void ROIAlign_transpose_kernel(
    const float* __restrict__ in, float* __restrict__ outT)
{
    __shared__ float tile[32][33];   // +1 pad: conflict-free transpose
    const int b  = blockIdx.z;
    const int t0 = blockIdx.x * 32;
    const int c0 = blockIdx.y * 32;
    const int tx = threadIdx.x;      // 0..31 (along t on read, along c on write)
    const int ty = threadIdx.y;      // 0..7

    const float* p = in + ((size_t)b * CH + c0) * TT + t0;
    #pragma unroll
    for (int i = ty; i < 32; i += 8)
        tile[i][tx] = p[(size_t)i * TT + tx];     // coalesced along t

    __syncthreads();

    float* q = outT + ((size_t)b * TT + t0) * CH + c0;
    #pragma unroll
    for (int i = ty; i < 32; i += 8)
        q[(size_t)i * CH + tx] = tile[tx][i];     // coalesced along c
}

// ---------------------------------------------------------------------------
// Main kernel, specialized fd == 32.
// 1 block per ROI, 256 threads = 256 channels. Each thread accumulates all
// 32 feature bins in registers (statically unrolled -> stays in VGPRs),
// reads are coalesced 256B wave-loads from the transposed input (t_lo is
// wave-uniform), writes are 8x float4 per thread.
// ---------------------------------------------------------------------------
__global__ __launch_bounds__(256) void ROIAlign_fd32_kernel(
    const float* __restrict__ inT,     // (BS, TT, CH)
    const float* __restrict__ rois,    // (N, 3)
    const int*   __restrict__ ratio_p,
    float*       __restrict__ out)     // (N, CH, 32)
{
    const int n = blockIdx.x;
    const int c = threadIdx.x;

    const int   ratio     = ratio_p[0];
    const float inv_ratio = 1.0f / (float)ratio;

    const float bf    = rois[3 * n + 0];
    const float start = rois[3 * n + 1];
    const float end   = rois[3 * n + 2];
    const int   b     = (int)bf;
    const float roi_len = fmaxf(end - start, 1.0f);
    const float bin     = roi_len / 32.0f;

    const float* base = inT + (size_t)b * TT * CH + c;

    float acc[32];
    #pragma unroll
    for (int f = 0; f < 32; ++f) {
        float a = 0.0f;
        for (int r = 0; r < ratio; ++r) {
            const float off = (float)f + ((float)r + 0.5f) * inv_ratio;
            const float t   = start + off * bin;          // unclipped
            if (t >= -1.0f && t <= (float)TT) {           // uniform branch
                float tc  = fminf(fmaxf(t, 0.0f), (float)(TT - 1));
                int   lo  = (int)tc;                      // tc >= 0: trunc==floor
                int   hi  = min(lo + 1, TT - 1);
                float frac = tc - (float)lo;
                float vlo = base[(size_t)lo * CH];        // coalesced across lanes
                float vhi = base[(size_t)hi * CH];
                a += vlo * (1.0f - frac) + vhi * frac;    // match reference rounding
            }
        }
        acc[f] = a * inv_ratio;                           // mean over ratio
    }

    float4* o = (float4*)(out + ((size_t)n * CH + c) * 32);
    #pragma unroll
    for (int k = 0; k < 8; ++k)
        o[k] = make_float4(acc[4 * k], acc[4 * k + 1], acc[4 * k + 2], acc[4 * k + 3]);
}

// ---------------------------------------------------------------------------
// Generic fallback (any fd, no transpose): 1 block per ROI, element-per-thread
// with coalesced writes and gathered reads from the original layout.
// ---------------------------------------------------------------------------
__global__ __launch_bounds__(256) void ROIAlign_generic_kernel(
    const float* __restrict__ in,      // (BS, CH, TT)
    const float* __restrict__ rois,
    const int*   __restrict__ ratio_p,
    float*       __restrict__ out,     // (N, CH, fd)
    int fd)
{
    const int n = blockIdx.x;
    const int   ratio     = ratio_p[0];
    const float inv_ratio = 1.0f / (float)ratio;

    const float bf    = rois[3 * n + 0];
    const float start = rois[3 * n + 1];
    const float end   = rois[3 * n + 2];
    const int   b     = (int)bf;
    const float roi_len = fmaxf(end - start, 1.0f);
    const float bin     = roi_len / (float)fd;

    const int total = CH * fd;
    for (int idx = threadIdx.x; idx < total; idx += blockDim.x) {
        const int c = idx / fd;
        const int f = idx % fd;
        const float* base = in + ((size_t)b * CH + c) * TT;
        float a = 0.0f;
        for (int r = 0; r < ratio; ++r) {
            const float off = (float)f + ((float)r + 0.5f) * inv_ratio;
            const float t   = start + off * bin;
            if (t >= -1.0f && t <= (float)TT) {
                float tc  = fminf(fmaxf(t, 0.0f), (float)(TT - 1));
                int   lo  = (int)tc;
                int   hi  = min(lo + 1, TT - 1);
                float frac = tc - (float)lo;
                float vlo = base[lo];
                float vhi = base[hi];
                a += vlo * (1.0f - frac) + vhi * frac;
            }
        }
        out[(size_t)n * total + idx] = a * inv_ratio;
    }
}

extern "C" void kernel_launch(void* const* d_in, const int* in_sizes, int n_in,
                              void* d_out, int out_size, void* d_ws, size_t ws_size,
                              hipStream_t stream) {
    const float* in      = (const float*)d_in[0];
    const float* rois    = (const float*)d_in[1];
    const int*   ratio_p = (const int*)d_in[3];
    float*       out     = (float*)d_out;

    const int N  = in_sizes[1] / 3;
    const int fd = out_size / (N * CH);
    const size_t transpose_bytes = (size_t)BS * CH * TT * sizeof(float);

    const bool fast = (fd == 32) &&
                      (ws_size >= transpose_bytes) &&
                      (in_sizes[0] == BS * CH * TT);

    if (fast) {
        float* inT = (float*)d_ws;
        dim3 tb(32, 8, 1);
        dim3 tg(TT / 32, CH / 32, BS);
        hipLaunchKernelGGL(ROIAlign_transpose_kernel, tg, tb, 0, stream, in, inT);
        hipLaunchKernelGGL(ROIAlign_fd32_kernel, dim3(N), dim3(256), 0, stream,
                           inT, rois, ratio_p, out);
    } else {
        hipLaunchKernelGGL(ROIAlign_generic_kernel, dim3(N), dim3(256), 0, stream,
                           in, rois, ratio_p, out, fd);
    }
}

// Round 2
// 106.738 us; speedup vs baseline: 1.0587x; 1.0587x over previous
//
#include <hip/hip_runtime.h>

#define BS 16
#define CH 256
#define TT 2048

// ---------------------------------------------------------------------------
// Transpose input (BS, CH, TT) -> (BS, TT, CH) so per-tap reads across
// channels are coalesced (lane = channel block, t is wave-uniform).
// Runs at ~5.2 TB/s for 67 MB (~13 us) — near ceiling.
// ---------------------------------------------------------------------------
__global__ __launch_bounds__(256) void ROIAlign_transpose_kernel(
    const float* __restrict__ in, float* __restrict__ outT)
{
    __shared__ float tile[32][33];   // +1 pad: conflict-free transpose
    const int b  = blockIdx.z;
    const int t0 = blockIdx.x * 32;
    const int c0 = blockIdx.y * 32;
    const int tx = threadIdx.x;      // 0..31
    const int ty = threadIdx.y;      // 0..7

    const float* p = in + ((size_t)b * CH + c0) * TT + t0;
    #pragma unroll
    for (int i = ty; i < 32; i += 8)
        tile[i][tx] = p[(size_t)i * TT + tx];     // coalesced along t

    __syncthreads();

    float* q = outT + ((size_t)b * TT + t0) * CH + c0;
    #pragma unroll
    for (int i = ty; i < 32; i += 8)
        q[(size_t)i * CH + tx] = tile[tx][i];     // coalesced along c
}

// ---------------------------------------------------------------------------
// Main kernel, fd == 32. ratio==2 fast path is fully unrolled (the runtime
// ratio loop in R0 blocked unrolling -> 40% VALUBusy, VGPR=24, few loads in
// flight). Fast path: lane l owns channels 4l..4l+3 (float4 taps: one
// wave-load = one full 1KB channel row), wave w owns f-bins 8w..8w+7.
// Accumulator float[8][4], all statically indexed -> pure VGPRs.
// ---------------------------------------------------------------------------
__global__ __launch_bounds__(256) void ROIAlign_fd32_kernel(
    const float* __restrict__ inT,     // (BS, TT, CH)
    const float* __restrict__ rois,    // (N, 3)
    const int*   __restrict__ ratio_p,
    float*       __restrict__ out)     // (N, CH, 32)
{
    const int n   = blockIdx.x;
    const int tid = threadIdx.x;

    const int   b      = (int)rois[3 * n + 0];
    const float bstart = rois[3 * n + 1];
    const float bend   = rois[3 * n + 2];
    const float roi_len = fmaxf(bend - bstart, 1.0f);
    const float bin     = roi_len * (1.0f / 32.0f);
    const int   ratio   = ratio_p[0];

    if (ratio == 2) {
        const int w = tid >> 6;          // wave -> f-bin block
        const int l = tid & 63;          // lane -> channel/4
        const float* base = inT + (size_t)b * (TT * CH) + 4 * l;

        float acc[8][4];
        #pragma unroll
        for (int i = 0; i < 8; ++i)
            #pragma unroll
            for (int j = 0; j < 4; ++j) acc[i][j] = 0.0f;

        #pragma unroll
        for (int i = 0; i < 8; ++i) {
            const float fbin = (float)(w * 8 + i);
            #pragma unroll
            for (int r = 0; r < 2; ++r) {
                const float t = bstart + (fbin + (r ? 0.75f : 0.25f)) * bin;
                if (t >= -1.0f && t <= (float)TT) {            // wave-uniform
                    float tc = fminf(fmaxf(t, 0.0f), (float)(TT - 1));
                    int   lo = (int)tc;                        // tc>=0: trunc==floor
                    int   hi = min(lo + 1, TT - 1);
                    float fr = tc - (float)lo;
                    const float4 vlo = *(const float4*)(base + (size_t)lo * CH);
                    const float4 vhi = *(const float4*)(base + (size_t)hi * CH);
                    acc[i][0] += vlo.x + fr * (vhi.x - vlo.x);
                    acc[i][1] += vlo.y + fr * (vhi.y - vlo.y);
                    acc[i][2] += vlo.z + fr * (vhi.z - vlo.z);
                    acc[i][3] += vlo.w + fr * (vhi.w - vlo.w);
                }
            }
            #pragma unroll
            for (int j = 0; j < 4; ++j) acc[i][j] *= 0.5f;     // mean over ratio=2
        }

        // channel 4l+j gets f-bins [8w, 8w+8): two float4 stores per channel
        float* o = out + ((size_t)n * CH + 4 * l) * 32 + w * 8;
        #pragma unroll
        for (int j = 0; j < 4; ++j) {
            *(float4*)(o + (size_t)j * 32) =
                make_float4(acc[0][j], acc[1][j], acc[2][j], acc[3][j]);
            *(float4*)(o + (size_t)j * 32 + 4) =
                make_float4(acc[4][j], acc[5][j], acc[6][j], acc[7][j]);
        }
    } else {
        // generic-ratio path: thread = channel, scalar taps (R0 structure)
        const int c = tid;
        const float inv_ratio = 1.0f / (float)ratio;
        const float* base = inT + (size_t)b * (TT * CH) + c;
        for (int f = 0; f < 32; ++f) {
            float a = 0.0f;
            for (int r = 0; r < ratio; ++r) {
                const float off = (float)f + ((float)r + 0.5f) * inv_ratio;
                const float t   = bstart + off * bin;
                if (t >= -1.0f && t <= (float)TT) {
                    float tc = fminf(fmaxf(t, 0.0f), (float)(TT - 1));
                    int   lo = (int)tc;
                    int   hi = min(lo + 1, TT - 1);
                    float fr = tc - (float)lo;
                    a += base[(size_t)lo * CH] * (1.0f - fr)
                       + base[(size_t)hi * CH] * fr;
                }
            }
            out[((size_t)n * CH + c) * 32 + f] = a * inv_ratio;
        }
    }
}

// ---------------------------------------------------------------------------
// Generic fallback (any fd, no transpose).
// ---------------------------------------------------------------------------
__global__ __launch_bounds__(256) void ROIAlign_generic_kernel(
    const float* __restrict__ in,      // (BS, CH, TT)
    const float* __restrict__ rois,
    const int*   __restrict__ ratio_p,
    float*       __restrict__ out,     // (N, CH, fd)
    int fd)
{
    const int n = blockIdx.x;
    const int   ratio     = ratio_p[0];
    const float inv_ratio = 1.0f / (float)ratio;

    const int   b      = (int)rois[3 * n + 0];
    const float bstart = rois[3 * n + 1];
    const float bend   = rois[3 * n + 2];
    const float roi_len = fmaxf(bend - bstart, 1.0f);
    const float bin     = roi_len / (float)fd;

    const int total = CH * fd;
    for (int idx = threadIdx.x; idx < total; idx += blockDim.x) {
        const int c = idx / fd;
        const int f = idx % fd;
        const float* base = in + ((size_t)b * CH + c) * TT;
        float a = 0.0f;
        for (int r = 0; r < ratio; ++r) {
            const float off = (float)f + ((float)r + 0.5f) * inv_ratio;
            const float t   = bstart + off * bin;
            if (t >= -1.0f && t <= (float)TT) {
                float tc = fminf(fmaxf(t, 0.0f), (float)(TT - 1));
                int   lo = (int)tc;
                int   hi = min(lo + 1, TT - 1);
                float fr = tc - (float)lo;
                a += base[lo] * (1.0f - fr) + base[hi] * fr;
            }
        }
        out[(size_t)n * total + idx] = a * inv_ratio;
    }
}

extern "C" void kernel_launch(void* const* d_in, const int* in_sizes, int n_in,
                              void* d_out, int out_size, void* d_ws, size_t ws_size,
                              hipStream_t stream) {
    const float* in      = (const float*)d_in[0];
    const float* rois    = (const float*)d_in[1];
    const int*   ratio_p = (const int*)d_in[3];
    float*       out     = (float*)d_out;

    const int N  = in_sizes[1] / 3;
    const int fd = out_size / (N * CH);
    const size_t transpose_bytes = (size_t)BS * CH * TT * sizeof(float);

    const bool fast = (fd == 32) &&
                      (ws_size >= transpose_bytes) &&
                      (in_sizes[0] == BS * CH * TT);

    if (fast) {
        float* inT = (float*)d_ws;
        dim3 tb(32, 8, 1);
        dim3 tg(TT / 32, CH / 32, BS);
        hipLaunchKernelGGL(ROIAlign_transpose_kernel, tg, tb, 0, stream, in, inT);
        hipLaunchKernelGGL(ROIAlign_fd32_kernel, dim3(N), dim3(256), 0, stream,
                           inT, rois, ratio_p, out);
    } else {
        hipLaunchKernelGGL(ROIAlign_generic_kernel, dim3(N), dim3(256), 0, stream,
                           in, rois, ratio_p, out, fd);
    }
}

// Round 3
// 79.068 us; speedup vs baseline: 1.4292x; 1.3499x over previous
//
#include <hip/hip_runtime.h>

#define BS 16
#define CH 256
#define TT 2048
#define NBINS 512   // 16 batches x 32 start-buckets

// ---------------------------------------------------------------------------
// Transpose input (BS, CH, TT) -> (BS, TT, CH). ~13 us @ ~5.2 TB/s.
// ---------------------------------------------------------------------------
__global__ __launch_bounds__(256) void ROIAlign_transpose_kernel(
    const float* __restrict__ in, float* __restrict__ outT)
{
    __shared__ float tile[32][33];
    const int b  = blockIdx.z;
    const int t0 = blockIdx.x * 32;
    const int c0 = blockIdx.y * 32;
    const int tx = threadIdx.x;
    const int ty = threadIdx.y;

    const float* p = in + ((size_t)b * CH + c0) * TT + t0;
    #pragma unroll
    for (int i = ty; i < 32; i += 8)
        tile[i][tx] = p[(size_t)i * TT + tx];

    __syncthreads();

    float* q = outT + ((size_t)b * TT + t0) * CH + c0;
    #pragma unroll
    for (int i = ty; i < 32; i += 8)
        q[(size_t)i * CH + tx] = tile[tx][i];
}

// ---------------------------------------------------------------------------
// Bin ROIs by (batch, start-bucket) -> perm. Single block, LDS hist + scan +
// scatter. Output perm is a permutation of [0,N); within-bin order is
// atomic-arrival (nondeterministic) but each ROI's output is computed and
// written identically regardless of order -> d_out deterministic.
// ---------------------------------------------------------------------------
__global__ __launch_bounds__(1024) void ROIAlign_sort_kernel(
    const float* __restrict__ rois, int N, int* __restrict__ perm)
{
    __shared__ int hist[NBINS];
    __shared__ int waveSums[16];
    const int tid = threadIdx.x;

    for (int i = tid; i < NBINS; i += 1024) hist[i] = 0;
    __syncthreads();

    for (int n = tid; n < N; n += 1024) {
        const int   b  = (int)rois[3 * n];
        const float s  = rois[3 * n + 1];
        const int   sb = min(31, max(0, (int)(s * (1.0f / 64.0f))));  // TT/32 = 64
        atomicAdd(&hist[b * 32 + sb], 1);
    }
    __syncthreads();

    // exclusive scan of hist[NBINS]: wave-level shfl scan + serial wave offsets
    const int own = (tid < NBINS) ? hist[tid] : 0;
    int v = own;
    #pragma unroll
    for (int d = 1; d < 64; d <<= 1) {
        int u = __shfl_up(v, d, 64);
        if ((int)(tid & 63) >= d) v += u;
    }
    if (tid < NBINS && (tid & 63) == 63) waveSums[tid >> 6] = v;
    __syncthreads();
    if (tid == 0) {
        int run = 0;
        #pragma unroll
        for (int i = 0; i < (NBINS / 64); ++i) {
            int c = waveSums[i]; waveSums[i] = run; run += c;
        }
    }
    __syncthreads();
    if (tid < NBINS) hist[tid] = v - own + waveSums[tid >> 6];
    __syncthreads();

    for (int n = tid; n < N; n += 1024) {
        const int   b  = (int)rois[3 * n];
        const float s  = rois[3 * n + 1];
        const int   sb = min(31, max(0, (int)(s * (1.0f / 64.0f))));
        const int pos = atomicAdd(&hist[b * 32 + sb], 1);
        perm[pos] = n;
    }
}

// ---------------------------------------------------------------------------
// Main kernel, fd == 32, ratio==2 fast path. Lane l owns channels 4l..4l+3
// (float4 taps), wave w owns f-bins 8w..8w+7. Taps are predicated (no
// branches) so loads pipeline. Blocks process sorted ROIs, chunked per XCD:
// sidx = (bid&7)*chunk + bid>>3 inverts the round-robin XCD assignment so
// each XCD works a contiguous (b, t)-range (~4MB ~= its L2).
// ---------------------------------------------------------------------------
__global__ __launch_bounds__(256) void ROIAlign_fd32_kernel(
    const float* __restrict__ inT,     // (BS, TT, CH)
    const float* __restrict__ rois,    // (N, 3)
    const int*   __restrict__ ratio_p,
    const int*   __restrict__ perm,    // may be null
    float*       __restrict__ out)     // (N, CH, 32)
{
    int m;
    if (perm) {
        const int chunk = gridDim.x >> 3;
        const int sidx  = (blockIdx.x & 7) * chunk + (blockIdx.x >> 3);
        m = perm[sidx];
    } else {
        m = blockIdx.x;
    }
    const int tid = threadIdx.x;

    const int   b      = (int)rois[3 * m + 0];
    const float bstart = rois[3 * m + 1];
    const float bend   = rois[3 * m + 2];
    const float roi_len = fmaxf(bend - bstart, 1.0f);
    const float bin     = roi_len * (1.0f / 32.0f);
    const int   ratio   = ratio_p[0];

    if (ratio == 2) {
        const int w = tid >> 6;
        const int l = tid & 63;
        const float* base = inT + (size_t)b * (TT * CH) + 4 * l;

        float acc[8][4];
        #pragma unroll
        for (int i = 0; i < 8; ++i)
            #pragma unroll
            for (int j = 0; j < 4; ++j) acc[i][j] = 0.0f;

        #pragma unroll
        for (int i = 0; i < 8; ++i) {
            const float fbin = (float)(w * 8 + i);
            #pragma unroll
            for (int r = 0; r < 2; ++r) {
                const float t  = bstart + (fbin + (r ? 0.75f : 0.25f)) * bin;
                const float wv = (t >= -1.0f && t <= (float)TT) ? 0.5f : 0.0f;
                float tc = fminf(fmaxf(t, 0.0f), (float)(TT - 1));
                int   lo = (int)tc;
                int   hi = min(lo + 1, TT - 1);
                float fr = tc - (float)lo;
                const float4 vlo = *(const float4*)(base + (size_t)lo * CH);
                const float4 vhi = *(const float4*)(base + (size_t)hi * CH);
                acc[i][0] += wv * (vlo.x + fr * (vhi.x - vlo.x));
                acc[i][1] += wv * (vlo.y + fr * (vhi.y - vlo.y));
                acc[i][2] += wv * (vlo.z + fr * (vhi.z - vlo.z));
                acc[i][3] += wv * (vlo.w + fr * (vhi.w - vlo.w));
            }
        }

        float* o = out + ((size_t)m * CH + 4 * l) * 32 + w * 8;
        #pragma unroll
        for (int j = 0; j < 4; ++j) {
            *(float4*)(o + (size_t)j * 32) =
                make_float4(acc[0][j], acc[1][j], acc[2][j], acc[3][j]);
            *(float4*)(o + (size_t)j * 32 + 4) =
                make_float4(acc[4][j], acc[5][j], acc[6][j], acc[7][j]);
        }
    } else {
        const int c = tid;
        const float inv_ratio = 1.0f / (float)ratio;
        const float* base = inT + (size_t)b * (TT * CH) + c;
        for (int f = 0; f < 32; ++f) {
            float a = 0.0f;
            for (int r = 0; r < ratio; ++r) {
                const float off = (float)f + ((float)r + 0.5f) * inv_ratio;
                const float t   = bstart + off * bin;
                if (t >= -1.0f && t <= (float)TT) {
                    float tc = fminf(fmaxf(t, 0.0f), (float)(TT - 1));
                    int   lo = (int)tc;
                    int   hi = min(lo + 1, TT - 1);
                    float fr = tc - (float)lo;
                    a += base[(size_t)lo * CH] * (1.0f - fr)
                       + base[(size_t)hi * CH] * fr;
                }
            }
            out[((size_t)m * CH + c) * 32 + f] = a * inv_ratio;
        }
    }
}

// ---------------------------------------------------------------------------
// Generic fallback (any fd, no transpose).
// ---------------------------------------------------------------------------
__global__ __launch_bounds__(256) void ROIAlign_generic_kernel(
    const float* __restrict__ in,      // (BS, CH, TT)
    const float* __restrict__ rois,
    const int*   __restrict__ ratio_p,
    float*       __restrict__ out,     // (N, CH, fd)
    int fd)
{
    const int n = blockIdx.x;
    const int   ratio     = ratio_p[0];
    const float inv_ratio = 1.0f / (float)ratio;

    const int   b      = (int)rois[3 * n + 0];
    const float bstart = rois[3 * n + 1];
    const float bend   = rois[3 * n + 2];
    const float roi_len = fmaxf(bend - bstart, 1.0f);
    const float bin     = roi_len / (float)fd;

    const int total = CH * fd;
    for (int idx = threadIdx.x; idx < total; idx += blockDim.x) {
        const int c = idx / fd;
        const int f = idx % fd;
        const float* base = in + ((size_t)b * CH + c) * TT;
        float a = 0.0f;
        for (int r = 0; r < ratio; ++r) {
            const float off = (float)f + ((float)r + 0.5f) * inv_ratio;
            const float t   = bstart + off * bin;
            if (t >= -1.0f && t <= (float)TT) {
                float tc = fminf(fmaxf(t, 0.0f), (float)(TT - 1));
                int   lo = (int)tc;
                int   hi = min(lo + 1, TT - 1);
                float fr = tc - (float)lo;
                a += base[lo] * (1.0f - fr) + base[hi] * fr;
            }
        }
        out[(size_t)n * total + idx] = a * inv_ratio;
    }
}

extern "C" void kernel_launch(void* const* d_in, const int* in_sizes, int n_in,
                              void* d_out, int out_size, void* d_ws, size_t ws_size,
                              hipStream_t stream) {
    const float* in      = (const float*)d_in[0];
    const float* rois    = (const float*)d_in[1];
    const int*   ratio_p = (const int*)d_in[3];
    float*       out     = (float*)d_out;

    const int N  = in_sizes[1] / 3;
    const int fd = out_size / (N * CH);
    const size_t transpose_bytes = (size_t)BS * CH * TT * sizeof(float);
    const size_t perm_bytes      = (size_t)N * sizeof(int);

    const bool fast = (fd == 32) &&
                      (ws_size >= transpose_bytes) &&
                      (in_sizes[0] == BS * CH * TT);

    if (fast) {
        float* inT = (float*)d_ws;
        const bool sorted = (ws_size >= transpose_bytes + perm_bytes) &&
                            (N % 8 == 0) && (N <= 1 << 20);
        int* perm = sorted ? (int*)((char*)d_ws + transpose_bytes) : nullptr;

        if (sorted)
            hipLaunchKernelGGL(ROIAlign_sort_kernel, dim3(1), dim3(1024), 0, stream,
                               rois, N, perm);

        dim3 tb(32, 8, 1);
        dim3 tg(TT / 32, CH / 32, BS);
        hipLaunchKernelGGL(ROIAlign_transpose_kernel, tg, tb, 0, stream, in, inT);
        hipLaunchKernelGGL(ROIAlign_fd32_kernel, dim3(N), dim3(256), 0, stream,
                           inT, rois, ratio_p, perm, out);
    } else {
        hipLaunchKernelGGL(ROIAlign_generic_kernel, dim3(N), dim3(256), 0, stream,
                           in, rois, ratio_p, out, fd);
    }
}